// Round 2
// baseline (1241.788 us; speedup 1.0000x reference)
//
#include <hip/hip_runtime.h>
#include <cstdint>
#include <cstddef>

#define N_NODES 40000
#define N_EDGES 640000
#define CH 128
#define NL 3
#define NB 64
#define LN_EPS 1e-5f

typedef short short8 __attribute__((ext_vector_type(8)));
typedef float floatx4 __attribute__((ext_vector_type(4)));

__device__ __forceinline__ unsigned short bf16_rne(float f) {
    unsigned int u = __float_as_uint(f);
    unsigned int r = u + 0x7FFF + ((u >> 16) & 1);
    return (unsigned short)(r >> 16);
}

// ---------------------------------------------------------------- CSR build

__global__ void deg_kernel(const int* __restrict__ ei, int* __restrict__ degi) {
    int e = blockIdx.x * 256 + threadIdx.x;
    if (e < N_EDGES) atomicAdd(&degi[ei[N_EDGES + e]], 1);
}

__global__ void isq_kernel(const int* __restrict__ degi, float* __restrict__ isq) {
    int n = blockIdx.x * 256 + threadIdx.x;
    if (n < N_NODES) isq[n] = rsqrtf((float)degi[n] + 1.0f);
}

__global__ void scan1_kernel(const int* __restrict__ degi, int* __restrict__ rowptr,
                             int* __restrict__ bsum) {
    __shared__ int s[256];
    int t = threadIdx.x;
    int i = blockIdx.x * 256 + t;
    int v = (i < N_NODES) ? degi[i] : 0;
    s[t] = v;
    __syncthreads();
    for (int off = 1; off < 256; off <<= 1) {
        int add = (t >= off) ? s[t - off] : 0;
        __syncthreads();
        s[t] += add;
        __syncthreads();
    }
    if (i < N_NODES) rowptr[i + 1] = s[t];
    if (t == 255) bsum[blockIdx.x] = s[255];
}

__global__ void scan2_kernel(int* __restrict__ bsum, int* __restrict__ boff, int nb) {
    __shared__ int s[256];
    int t = threadIdx.x;
    int v = (t < nb) ? bsum[t] : 0;
    s[t] = v;
    __syncthreads();
    for (int off = 1; off < 256; off <<= 1) {
        int add = (t >= off) ? s[t - off] : 0;
        __syncthreads();
        s[t] += add;
        __syncthreads();
    }
    if (t < nb) boff[t] = s[t] - v;  // exclusive
}

__global__ void scan3_kernel(int* __restrict__ rowptr, const int* __restrict__ boff) {
    int i = blockIdx.x * 256 + threadIdx.x;
    if (i < N_NODES) rowptr[i + 1] += boff[blockIdx.x];
    if (i == 0 && blockIdx.x == 0) rowptr[0] = 0;
}

__global__ void fill_csr_kernel(const int* __restrict__ ei, const int* __restrict__ rowptr,
                                int* __restrict__ fill, int* __restrict__ srcs) {
    int e = blockIdx.x * 256 + threadIdx.x;
    if (e < N_EDGES) {
        int s = ei[e];
        int d = ei[N_EDGES + e];
        int pos = atomicAdd(&fill[d], 1);
        srcs[rowptr[d] + pos] = s;
    }
}

// ---------------------------------------------------------------- W packing
// Pack 8 fp32 128x128 matrices into hi/lo bf16 B-fragment layout for
// mfma_f32_16x16x32_bf16:  dst[((kk*4+quad)*128 + n)*8 + j], k = kk*32+quad*8+j
__global__ void pack_w_kernel(const float* __restrict__ pre_w, const float* __restrict__ conv_w,
                              const float* __restrict__ ffn_w1, const float* __restrict__ ffn_w2,
                              short* __restrict__ hi, short* __restrict__ lo) {
    int idx = blockIdx.x * 256 + threadIdx.x;  // 8 * 16384 total
    int mat = idx >> 14;
    int e = idx & 16383;
    int k = e >> 7, n = e & 127;
    const float* src;
    switch (mat) {
        case 0: src = pre_w; break;
        case 1: case 2: case 3: src = conv_w + (size_t)(mat - 1) * 16384; break;
        case 4: case 5: src = ffn_w1 + (size_t)(mat - 4) * 16384; break;
        default: src = ffn_w2 + (size_t)(mat - 6) * 16384; break;
    }
    float f = src[e];
    unsigned short h = bf16_rne(f);
    float hf = __uint_as_float((unsigned)h << 16);
    unsigned short l = bf16_rne(f - hf);
    int kk = k >> 5, quad = (k >> 3) & 3, j = k & 7;
    int dst = (mat << 14) + (((kk * 4 + quad) * 128 + n) * 8 + j);
    hi[dst] = (short)h;
    lo[dst] = (short)l;
}

// ---------------------------------------------------------------- MFMA GEMM
// C[40000x128] = A[40000x128] @ W[128x128] via split-bf16 (3 mfma terms).
// Block = 4 waves, 64 rows; wave -> 16 rows x 128 cols (8 tiles of 16x16).
// A read as fp32, split to hi/lo bf16 in-registers.
template <int MODE>  // 0: +bias, 1: bias+relu, 2: bias+residual
__launch_bounds__(256, 4)
__global__ void gemm_mfma(const float* __restrict__ A, const short* __restrict__ Whi,
                          const short* __restrict__ Wlo, const float* __restrict__ bias,
                          const float* __restrict__ Res, float* __restrict__ Out) {
    const int lane = threadIdx.x & 63;
    const int wv = threadIdx.x >> 6;
    const int row0 = blockIdx.x * 64 + wv * 16;
    const int m = lane & 15;
    const int quad = lane >> 4;

    floatx4 acc[8];
#pragma unroll
    for (int c = 0; c < 8; ++c) acc[c] = (floatx4){0.f, 0.f, 0.f, 0.f};

    const float* arow = A + (size_t)(row0 + m) * CH + quad * 8;

#pragma unroll
    for (int kk = 0; kk < 4; ++kk) {
        float4 a0 = *(const float4*)(arow + kk * 32);
        float4 a1 = *(const float4*)(arow + kk * 32 + 4);
        float av[8] = {a0.x, a0.y, a0.z, a0.w, a1.x, a1.y, a1.z, a1.w};
        short8 ahi, alo;
#pragma unroll
        for (int j = 0; j < 8; ++j) {
            unsigned short h = bf16_rne(av[j]);
            ahi[j] = (short)h;
            alo[j] = (short)bf16_rne(av[j] - __uint_as_float((unsigned)h << 16));
        }
        const short* wb_h = Whi + ((size_t)(kk * 4 + quad) * 128 + m) * 8;
        const short* wb_l = Wlo + ((size_t)(kk * 4 + quad) * 128 + m) * 8;
#pragma unroll
        for (int c = 0; c < 8; ++c) {
            short8 bhi = *(const short8*)(wb_h + c * 128);
            short8 blo = *(const short8*)(wb_l + c * 128);
            acc[c] = __builtin_amdgcn_mfma_f32_16x16x32_bf16(ahi, bhi, acc[c], 0, 0, 0);
            acc[c] = __builtin_amdgcn_mfma_f32_16x16x32_bf16(alo, bhi, acc[c], 0, 0, 0);
            acc[c] = __builtin_amdgcn_mfma_f32_16x16x32_bf16(ahi, blo, acc[c], 0, 0, 0);
        }
    }

#pragma unroll
    for (int c = 0; c < 8; ++c) {
        int col = c * 16 + m;
        float bv = bias ? bias[col] : 0.f;
#pragma unroll
        for (int r = 0; r < 4; ++r) {
            int row = row0 + quad * 4 + r;
            float v = acc[c][r] + bv;
            if (MODE == 1) v = fmaxf(v, 0.f);
            if (MODE == 2) v += Res[(size_t)row * CH + col];
            Out[(size_t)row * CH + col] = v;
        }
    }
}

// ---------------------------------------------------------------- aggregation
__launch_bounds__(256)
__global__ void agg_kernel(const float* __restrict__ HW, const int* __restrict__ rowptr,
                           const int* __restrict__ srcs, const float* __restrict__ isq,
                           const float* __restrict__ bias, float* __restrict__ Out) {
    const int lane = threadIdx.x & 63;
    const int node = blockIdx.x * 4 + (threadIdx.x >> 6);
    const int start = rowptr[node];
    const int end = rowptr[node + 1];

    float ax = 0.f, ay = 0.f;
    for (int base = start; base < end; base += 64) {
        int idx = base + lane;
        int clamped = (idx < end) ? idx : (end - 1);
        int sl = srcs[clamped];
        float wl = isq[sl];
        int cnt = end - base;
        if (cnt > 64) cnt = 64;
        for (int j = 0; j < cnt; ++j) {
            int s = __shfl(sl, j);
            float w = __shfl(wl, j);
            const float2 v = *(const float2*)(HW + (size_t)s * CH + lane * 2);
            ax = fmaf(w, v.x, ax);
            ay = fmaf(w, v.y, ay);
        }
    }
    float d = isq[node];
    const float2 hv = *(const float2*)(HW + (size_t)node * CH + lane * 2);
    const float2 bb = *(const float2*)(bias + lane * 2);
    float2 o;
    o.x = d * ax + d * d * hv.x + bb.x;
    o.y = d * ay + d * d * hv.y + bb.y;
    *(float2*)(Out + (size_t)node * CH + lane * 2) = o;
}

// ---------------------------------------------------------------- layernorm
template <int RELURES>
__launch_bounds__(256)
__global__ void ln_kernel(float* __restrict__ D, const float* __restrict__ S,
                          const float* __restrict__ gamma, const float* __restrict__ beta) {
    const int lane = threadIdx.x & 63;
    const int node = blockIdx.x * 4 + (threadIdx.x >> 6);
    const float2 x = *(const float2*)(S + (size_t)node * CH + lane * 2);
    float sum = x.x + x.y;
    float sq = x.x * x.x + x.y * x.y;
    for (int m = 1; m < 64; m <<= 1) {
        sum += __shfl_xor(sum, m);
        sq += __shfl_xor(sq, m);
    }
    float mean = sum * (1.f / CH);
    float var = sq * (1.f / CH) - mean * mean;
    float rstd = rsqrtf(var + LN_EPS);
    const float2 gg = *(const float2*)(gamma + lane * 2);
    const float2 bb = *(const float2*)(beta + lane * 2);
    float y0 = (x.x - mean) * rstd * gg.x + bb.x;
    float y1 = (x.y - mean) * rstd * gg.y + bb.y;
    float2* dp = (float2*)(D + (size_t)node * CH + lane * 2);
    if (RELURES) {
        float2 r = *dp;
        y0 = fmaxf(y0, 0.f) + r.x;
        y1 = fmaxf(y1, 0.f) + r.y;
    }
    float2 o; o.x = y0; o.y = y1;
    *dp = o;
}

// ---------------------------------------------------------------- pooling
__launch_bounds__(256)
__global__ void pool_kernel(const float* __restrict__ H, const int* __restrict__ batch,
                            float* __restrict__ g, float* __restrict__ cntf) {
    const int lane = threadIdx.x & 63;
    const int w = blockIdx.x * 4 + (threadIdx.x >> 6);
    const int n0 = w * 16;
    float lx = 0.f, ly = 0.f;
    int run = 0;
    int cur = batch[n0];
    for (int t = 0; t < 16; ++t) {
        int n = n0 + t;
        int b = batch[n];
        if (b != cur) {
            atomicAdd(&g[(size_t)cur * CH + lane * 2], lx);
            atomicAdd(&g[(size_t)cur * CH + lane * 2 + 1], ly);
            if (lane == 0) atomicAdd(&cntf[cur], (float)run);
            lx = ly = 0.f; run = 0; cur = b;
        }
        const float2 v = *(const float2*)(H + (size_t)n * CH + lane * 2);
        lx += v.x; ly += v.y; ++run;
    }
    atomicAdd(&g[(size_t)cur * CH + lane * 2], lx);
    atomicAdd(&g[(size_t)cur * CH + lane * 2 + 1], ly);
    if (lane == 0) atomicAdd(&cntf[cur], (float)run);
}

// ---------------------------------------------------------------- classifier
__launch_bounds__(128)
__global__ void cls_kernel(const float* __restrict__ g, const float* __restrict__ cntf,
                           const float* __restrict__ w1, const float* __restrict__ b1,
                           const float* __restrict__ w2, const float* __restrict__ b2,
                           float* __restrict__ out) {
    __shared__ float gm[CH];
    __shared__ float red[2];
    const int b = blockIdx.x;
    const int t = threadIdx.x;
    float inv = 1.f / fmaxf(cntf[b], 1.f);
    gm[t] = g[(size_t)b * CH + t] * inv;
    __syncthreads();
    float acc = b1[t];
    for (int k = 0; k < CH; ++k) acc = fmaf(gm[k], w1[(size_t)k * CH + t], acc);
    float v = fmaxf(acc, 0.f) * w2[t];
    for (int m = 1; m < 64; m <<= 1) v += __shfl_xor(v, m);
    if ((t & 63) == 0) red[t >> 6] = v;
    __syncthreads();
    if (t == 0) out[b] = red[0] + red[1] + b2[0];
}

// ---------------------------------------------------------------- launch

extern "C" void kernel_launch(void* const* d_in, const int* in_sizes, int n_in,
                              void* d_out, int out_size, void* d_ws, size_t ws_size,
                              hipStream_t stream) {
    const float* x      = (const float*)d_in[0];
    const int*   ei     = (const int*)d_in[1];
    const int*   batch  = (const int*)d_in[2];
    const float* pre_w  = (const float*)d_in[3];
    const float* pre_b  = (const float*)d_in[4];
    const float* conv_w = (const float*)d_in[5];
    const float* conv_b = (const float*)d_in[6];
    const float* ln_g   = (const float*)d_in[7];
    const float* ln_b   = (const float*)d_in[8];
    const float* ffn_w1 = (const float*)d_in[9];
    const float* ffn_b1 = (const float*)d_in[10];
    const float* ffn_w2 = (const float*)d_in[11];
    const float* ffn_b2 = (const float*)d_in[12];
    const float* fln_g  = (const float*)d_in[13];
    const float* fln_b  = (const float*)d_in[14];
    const float* cls_w1 = (const float*)d_in[15];
    const float* cls_b1 = (const float*)d_in[16];
    const float* cls_w2 = (const float*)d_in[17];
    const float* cls_b2 = (const float*)d_in[18];

    // workspace layout
    float* H    = (float*)d_ws;
    float* HWb  = H + (size_t)N_NODES * CH;
    float* T    = HWb + (size_t)N_NODES * CH;
    int*   degi = (int*)(T + (size_t)N_NODES * CH);
    int*   fill = degi + N_NODES;
    float* g    = (float*)(fill + N_NODES);       // zero zone: degi..cntf contiguous
    float* cntf = g + (size_t)NB * CH;
    float* isq  = cntf + NB;
    int*  rowptr = (int*)(isq + N_NODES);
    int*  bsum   = rowptr + N_NODES + 1;
    int*  boff   = bsum + 256;
    int*  srcs   = boff + 256;
    short* wphi  = (short*)(srcs + N_EDGES);       // 8 * 16384 shorts
    short* wplo  = wphi + 8 * 16384;

    const int nb_scan = (N_NODES + 255) / 256;  // 157

    hipMemsetAsync(degi, 0, (size_t)(2 * N_NODES + NB * CH + NB) * sizeof(int), stream);

    deg_kernel<<<N_EDGES / 256, 256, 0, stream>>>(ei, degi);
    isq_kernel<<<nb_scan, 256, 0, stream>>>(degi, isq);
    scan1_kernel<<<nb_scan, 256, 0, stream>>>(degi, rowptr, bsum);
    scan2_kernel<<<1, 256, 0, stream>>>(bsum, boff, nb_scan);
    scan3_kernel<<<nb_scan, 256, 0, stream>>>(rowptr, boff);
    fill_csr_kernel<<<N_EDGES / 256, 256, 0, stream>>>(ei, rowptr, fill, srcs);
    pack_w_kernel<<<8 * 16384 / 256, 256, 0, stream>>>(pre_w, conv_w, ffn_w1, ffn_w2,
                                                       wphi, wplo);

    const int gblk = N_NODES / 64;  // 625

    // pre-scaler: H = x @ pre_w + pre_b
    gemm_mfma<0><<<gblk, 256, 0, stream>>>(x, wphi, wplo, pre_b, nullptr, H);

    for (int i = 0; i < NL; ++i) {
        const short* cwh = wphi + (size_t)(1 + i) * 16384;
        const short* cwl = wplo + (size_t)(1 + i) * 16384;
        gemm_mfma<0><<<gblk, 256, 0, stream>>>(H, cwh, cwl, nullptr, nullptr, HWb);
        agg_kernel<<<N_NODES / 4, 256, 0, stream>>>(HWb, rowptr, srcs, isq,
                                                    conv_b + (size_t)i * CH, T);
        if (i < NL - 1) {
            // H = relu(LN(T)) + H
            ln_kernel<1><<<N_NODES / 4, 256, 0, stream>>>(H, T, ln_g + (size_t)i * CH,
                                                          ln_b + (size_t)i * CH);
            // T = relu(H @ w1 + b1)
            gemm_mfma<1><<<gblk, 256, 0, stream>>>(H, wphi + (size_t)(4 + i) * 16384,
                                                   wplo + (size_t)(4 + i) * 16384,
                                                   ffn_b1 + (size_t)i * CH, nullptr, T);
            // HWb = T @ w2 + b2 + H
            gemm_mfma<2><<<gblk, 256, 0, stream>>>(T, wphi + (size_t)(6 + i) * 16384,
                                                   wplo + (size_t)(6 + i) * 16384,
                                                   ffn_b2 + (size_t)i * CH, H, HWb);
            // H = LN(HWb)
            ln_kernel<0><<<N_NODES / 4, 256, 0, stream>>>(H, HWb, fln_g + (size_t)i * CH,
                                                          fln_b + (size_t)i * CH);
        }
    }

    pool_kernel<<<N_NODES / 64, 256, 0, stream>>>(T, batch, g, cntf);
    cls_kernel<<<NB, CH, 0, stream>>>(g, cntf, cls_w1, cls_b1, cls_w2, cls_b2,
                                      (float*)d_out);
}

// Round 3
// 599.283 us; speedup vs baseline: 2.0721x; 2.0721x over previous
//
#include <hip/hip_runtime.h>
#include <cstdint>
#include <cstddef>

#define N_NODES 40000
#define N_EDGES 640000
#define CH 128
#define NL 3
#define NB 64
#define LN_EPS 1e-5f

typedef short short8 __attribute__((ext_vector_type(8)));
typedef float floatx4 __attribute__((ext_vector_type(4)));

__device__ __forceinline__ unsigned short bf16_rne(float f) {
    unsigned int u = __float_as_uint(f);
    unsigned int r = u + 0x7FFF + ((u >> 16) & 1);
    return (unsigned short)(r >> 16);
}

// ---------------------------------------------------------------- CSR build

__global__ void deg_kernel(const int* __restrict__ ei, int* __restrict__ degi) {
    int e = blockIdx.x * 256 + threadIdx.x;
    if (e < N_EDGES) atomicAdd(&degi[ei[N_EDGES + e]], 1);
}

__global__ void isq_kernel(const int* __restrict__ degi, float* __restrict__ isq) {
    int n = blockIdx.x * 256 + threadIdx.x;
    if (n < N_NODES) isq[n] = rsqrtf((float)degi[n] + 1.0f);
}

__global__ void scan1_kernel(const int* __restrict__ degi, int* __restrict__ rowptr,
                             int* __restrict__ bsum) {
    __shared__ int s[256];
    int t = threadIdx.x;
    int i = blockIdx.x * 256 + t;
    int v = (i < N_NODES) ? degi[i] : 0;
    s[t] = v;
    __syncthreads();
    for (int off = 1; off < 256; off <<= 1) {
        int add = (t >= off) ? s[t - off] : 0;
        __syncthreads();
        s[t] += add;
        __syncthreads();
    }
    if (i < N_NODES) rowptr[i + 1] = s[t];
    if (t == 255) bsum[blockIdx.x] = s[255];
}

__global__ void scan2_kernel(int* __restrict__ bsum, int* __restrict__ boff, int nb) {
    __shared__ int s[256];
    int t = threadIdx.x;
    int v = (t < nb) ? bsum[t] : 0;
    s[t] = v;
    __syncthreads();
    for (int off = 1; off < 256; off <<= 1) {
        int add = (t >= off) ? s[t - off] : 0;
        __syncthreads();
        s[t] += add;
        __syncthreads();
    }
    if (t < nb) boff[t] = s[t] - v;  // exclusive
}

__global__ void scan3_kernel(int* __restrict__ rowptr, const int* __restrict__ boff) {
    int i = blockIdx.x * 256 + threadIdx.x;
    if (i < N_NODES) rowptr[i + 1] += boff[blockIdx.x];
    if (i == 0 && blockIdx.x == 0) rowptr[0] = 0;
}

__global__ void fill_csr_kernel(const int* __restrict__ ei, const int* __restrict__ rowptr,
                                int* __restrict__ fill, int* __restrict__ srcs) {
    int e = blockIdx.x * 256 + threadIdx.x;
    if (e < N_EDGES) {
        int s = ei[e];
        int d = ei[N_EDGES + e];
        int pos = atomicAdd(&fill[d], 1);
        srcs[rowptr[d] + pos] = s;
    }
}

// ---------------------------------------------------------------- W packing
// Pack 8 fp32 128x128 matrices into hi/lo bf16 B-fragment layout for
// mfma_f32_16x16x32_bf16:  dst[((kk*4+quad)*128 + n)*8 + j], k = kk*32+quad*8+j
__global__ void pack_w_kernel(const float* __restrict__ pre_w, const float* __restrict__ conv_w,
                              const float* __restrict__ ffn_w1, const float* __restrict__ ffn_w2,
                              short* __restrict__ hi, short* __restrict__ lo) {
    int idx = blockIdx.x * 256 + threadIdx.x;  // 8 * 16384 total
    int mat = idx >> 14;
    int e = idx & 16383;
    int k = e >> 7, n = e & 127;
    const float* src;
    switch (mat) {
        case 0: src = pre_w; break;
        case 1: case 2: case 3: src = conv_w + (size_t)(mat - 1) * 16384; break;
        case 4: case 5: src = ffn_w1 + (size_t)(mat - 4) * 16384; break;
        default: src = ffn_w2 + (size_t)(mat - 6) * 16384; break;
    }
    float f = src[e];
    unsigned short h = bf16_rne(f);
    float hf = __uint_as_float((unsigned)h << 16);
    unsigned short l = bf16_rne(f - hf);
    int kk = k >> 5, quad = (k >> 3) & 3, j = k & 7;
    int dst = (mat << 14) + (((kk * 4 + quad) * 128 + n) * 8 + j);
    hi[dst] = (short)h;
    lo[dst] = (short)l;
}

// ---------------------------------------------------------------- MFMA GEMM
// C[40000x128] = A[40000x128] @ W[128x128] via split-bf16 (3 mfma terms).
// Block = 4 waves, 64 rows; wave -> 16 rows x 128 cols (8 tiles of 16x16).
// kk loop is unroll-1 ON PURPOSE: full unroll hoists up to 64 B-fragment
// loads (256 VGPRs) and spills; launch_bounds(256,2) caps at 256 VGPRs.
template <int MODE>  // 0: +bias, 1: bias+relu, 2: bias+residual
__launch_bounds__(256, 2)
__global__ void gemm_mfma(const float* __restrict__ A, const short* __restrict__ Whi,
                          const short* __restrict__ Wlo, const float* __restrict__ bias,
                          const float* __restrict__ Res, float* __restrict__ Out) {
    const int lane = threadIdx.x & 63;
    const int wv = threadIdx.x >> 6;
    const int row0 = blockIdx.x * 64 + wv * 16;
    const int m = lane & 15;
    const int quad = lane >> 4;

    floatx4 acc[8];
#pragma unroll
    for (int c = 0; c < 8; ++c) acc[c] = (floatx4){0.f, 0.f, 0.f, 0.f};

    const float* arow = A + (size_t)(row0 + m) * CH + quad * 8;

#pragma unroll 1
    for (int kk = 0; kk < 4; ++kk) {
        float4 a0 = *(const float4*)(arow + kk * 32);
        float4 a1 = *(const float4*)(arow + kk * 32 + 4);
        float av[8] = {a0.x, a0.y, a0.z, a0.w, a1.x, a1.y, a1.z, a1.w};
        short8 ahi, alo;
#pragma unroll
        for (int j = 0; j < 8; ++j) {
            unsigned short h = bf16_rne(av[j]);
            ahi[j] = (short)h;
            alo[j] = (short)bf16_rne(av[j] - __uint_as_float((unsigned)h << 16));
        }
        const short* wb_h = Whi + ((size_t)(kk * 4 + quad) * 128 + m) * 8;
        const short* wb_l = Wlo + ((size_t)(kk * 4 + quad) * 128 + m) * 8;
#pragma unroll
        for (int c = 0; c < 8; ++c) {
            short8 bhi = *(const short8*)(wb_h + c * 128);
            short8 blo = *(const short8*)(wb_l + c * 128);
            acc[c] = __builtin_amdgcn_mfma_f32_16x16x32_bf16(ahi, bhi, acc[c], 0, 0, 0);
            acc[c] = __builtin_amdgcn_mfma_f32_16x16x32_bf16(alo, bhi, acc[c], 0, 0, 0);
            acc[c] = __builtin_amdgcn_mfma_f32_16x16x32_bf16(ahi, blo, acc[c], 0, 0, 0);
        }
    }

#pragma unroll
    for (int c = 0; c < 8; ++c) {
        int col = c * 16 + m;
        float bv = bias ? bias[col] : 0.f;
#pragma unroll
        for (int r = 0; r < 4; ++r) {
            int row = row0 + quad * 4 + r;
            float v = acc[c][r] + bv;
            if (MODE == 1) v = fmaxf(v, 0.f);
            if (MODE == 2) v += Res[(size_t)row * CH + col];
            Out[(size_t)row * CH + col] = v;
        }
    }
}

// ---------------------------------------------------------------- aggregation
__launch_bounds__(256)
__global__ void agg_kernel(const float* __restrict__ HW, const int* __restrict__ rowptr,
                           const int* __restrict__ srcs, const float* __restrict__ isq,
                           const float* __restrict__ bias, float* __restrict__ Out) {
    const int lane = threadIdx.x & 63;
    const int node = blockIdx.x * 4 + (threadIdx.x >> 6);
    const int start = rowptr[node];
    const int end = rowptr[node + 1];

    float ax = 0.f, ay = 0.f;
    for (int base = start; base < end; base += 64) {
        int idx = base + lane;
        int clamped = (idx < end) ? idx : (end - 1);
        int sl = srcs[clamped];
        float wl = isq[sl];
        int cnt = end - base;
        if (cnt > 64) cnt = 64;
        for (int j = 0; j < cnt; ++j) {
            int s = __shfl(sl, j);
            float w = __shfl(wl, j);
            const float2 v = *(const float2*)(HW + (size_t)s * CH + lane * 2);
            ax = fmaf(w, v.x, ax);
            ay = fmaf(w, v.y, ay);
        }
    }
    float d = isq[node];
    const float2 hv = *(const float2*)(HW + (size_t)node * CH + lane * 2);
    const float2 bb = *(const float2*)(bias + lane * 2);
    float2 o;
    o.x = d * ax + d * d * hv.x + bb.x;
    o.y = d * ay + d * d * hv.y + bb.y;
    *(float2*)(Out + (size_t)node * CH + lane * 2) = o;
}

// ---------------------------------------------------------------- layernorm
template <int RELURES>
__launch_bounds__(256)
__global__ void ln_kernel(float* __restrict__ D, const float* __restrict__ S,
                          const float* __restrict__ gamma, const float* __restrict__ beta) {
    const int lane = threadIdx.x & 63;
    const int node = blockIdx.x * 4 + (threadIdx.x >> 6);
    const float2 x = *(const float2*)(S + (size_t)node * CH + lane * 2);
    float sum = x.x + x.y;
    float sq = x.x * x.x + x.y * x.y;
    for (int m = 1; m < 64; m <<= 1) {
        sum += __shfl_xor(sum, m);
        sq += __shfl_xor(sq, m);
    }
    float mean = sum * (1.f / CH);
    float var = sq * (1.f / CH) - mean * mean;
    float rstd = rsqrtf(var + LN_EPS);
    const float2 gg = *(const float2*)(gamma + lane * 2);
    const float2 bb = *(const float2*)(beta + lane * 2);
    float y0 = (x.x - mean) * rstd * gg.x + bb.x;
    float y1 = (x.y - mean) * rstd * gg.y + bb.y;
    float2* dp = (float2*)(D + (size_t)node * CH + lane * 2);
    if (RELURES) {
        float2 r = *dp;
        y0 = fmaxf(y0, 0.f) + r.x;
        y1 = fmaxf(y1, 0.f) + r.y;
    }
    float2 o; o.x = y0; o.y = y1;
    *dp = o;
}

// ---------------------------------------------------------------- pooling
__launch_bounds__(256)
__global__ void pool_kernel(const float* __restrict__ H, const int* __restrict__ batch,
                            float* __restrict__ g, float* __restrict__ cntf) {
    const int lane = threadIdx.x & 63;
    const int w = blockIdx.x * 4 + (threadIdx.x >> 6);
    const int n0 = w * 16;
    float lx = 0.f, ly = 0.f;
    int run = 0;
    int cur = batch[n0];
    for (int t = 0; t < 16; ++t) {
        int n = n0 + t;
        int b = batch[n];
        if (b != cur) {
            atomicAdd(&g[(size_t)cur * CH + lane * 2], lx);
            atomicAdd(&g[(size_t)cur * CH + lane * 2 + 1], ly);
            if (lane == 0) atomicAdd(&cntf[cur], (float)run);
            lx = ly = 0.f; run = 0; cur = b;
        }
        const float2 v = *(const float2*)(H + (size_t)n * CH + lane * 2);
        lx += v.x; ly += v.y; ++run;
    }
    atomicAdd(&g[(size_t)cur * CH + lane * 2], lx);
    atomicAdd(&g[(size_t)cur * CH + lane * 2 + 1], ly);
    if (lane == 0) atomicAdd(&cntf[cur], (float)run);
}

// ---------------------------------------------------------------- classifier
__launch_bounds__(128)
__global__ void cls_kernel(const float* __restrict__ g, const float* __restrict__ cntf,
                           const float* __restrict__ w1, const float* __restrict__ b1,
                           const float* __restrict__ w2, const float* __restrict__ b2,
                           float* __restrict__ out) {
    __shared__ float gm[CH];
    __shared__ float red[2];
    const int b = blockIdx.x;
    const int t = threadIdx.x;
    float inv = 1.f / fmaxf(cntf[b], 1.f);
    gm[t] = g[(size_t)b * CH + t] * inv;
    __syncthreads();
    float acc = b1[t];
    for (int k = 0; k < CH; ++k) acc = fmaf(gm[k], w1[(size_t)k * CH + t], acc);
    float v = fmaxf(acc, 0.f) * w2[t];
    for (int m = 1; m < 64; m <<= 1) v += __shfl_xor(v, m);
    if ((t & 63) == 0) red[t >> 6] = v;
    __syncthreads();
    if (t == 0) out[b] = red[0] + red[1] + b2[0];
}

// ---------------------------------------------------------------- launch

extern "C" void kernel_launch(void* const* d_in, const int* in_sizes, int n_in,
                              void* d_out, int out_size, void* d_ws, size_t ws_size,
                              hipStream_t stream) {
    const float* x      = (const float*)d_in[0];
    const int*   ei     = (const int*)d_in[1];
    const int*   batch  = (const int*)d_in[2];
    const float* pre_w  = (const float*)d_in[3];
    const float* pre_b  = (const float*)d_in[4];
    const float* conv_w = (const float*)d_in[5];
    const float* conv_b = (const float*)d_in[6];
    const float* ln_g   = (const float*)d_in[7];
    const float* ln_b   = (const float*)d_in[8];
    const float* ffn_w1 = (const float*)d_in[9];
    const float* ffn_b1 = (const float*)d_in[10];
    const float* ffn_w2 = (const float*)d_in[11];
    const float* ffn_b2 = (const float*)d_in[12];
    const float* fln_g  = (const float*)d_in[13];
    const float* fln_b  = (const float*)d_in[14];
    const float* cls_w1 = (const float*)d_in[15];
    const float* cls_b1 = (const float*)d_in[16];
    const float* cls_w2 = (const float*)d_in[17];
    const float* cls_b2 = (const float*)d_in[18];

    // workspace layout
    float* H    = (float*)d_ws;
    float* HWb  = H + (size_t)N_NODES * CH;
    float* T    = HWb + (size_t)N_NODES * CH;
    int*   degi = (int*)(T + (size_t)N_NODES * CH);
    int*   fill = degi + N_NODES;
    float* g    = (float*)(fill + N_NODES);       // zero zone: degi..cntf contiguous
    float* cntf = g + (size_t)NB * CH;
    float* isq  = cntf + NB;
    int*  rowptr = (int*)(isq + N_NODES);
    int*  bsum   = rowptr + N_NODES + 1;
    int*  boff   = bsum + 256;
    int*  srcs   = boff + 256;
    short* wphi  = (short*)(srcs + N_EDGES);       // 8 * 16384 shorts
    short* wplo  = wphi + 8 * 16384;

    const int nb_scan = (N_NODES + 255) / 256;  // 157

    hipMemsetAsync(degi, 0, (size_t)(2 * N_NODES + NB * CH + NB) * sizeof(int), stream);

    deg_kernel<<<N_EDGES / 256, 256, 0, stream>>>(ei, degi);
    isq_kernel<<<nb_scan, 256, 0, stream>>>(degi, isq);
    scan1_kernel<<<nb_scan, 256, 0, stream>>>(degi, rowptr, bsum);
    scan2_kernel<<<1, 256, 0, stream>>>(bsum, boff, nb_scan);
    scan3_kernel<<<nb_scan, 256, 0, stream>>>(rowptr, boff);
    fill_csr_kernel<<<N_EDGES / 256, 256, 0, stream>>>(ei, rowptr, fill, srcs);
    pack_w_kernel<<<8 * 16384 / 256, 256, 0, stream>>>(pre_w, conv_w, ffn_w1, ffn_w2,
                                                       wphi, wplo);

    const int gblk = N_NODES / 64;  // 625

    // pre-scaler: H = x @ pre_w + pre_b
    gemm_mfma<0><<<gblk, 256, 0, stream>>>(x, wphi, wplo, pre_b, nullptr, H);

    for (int i = 0; i < NL; ++i) {
        const short* cwh = wphi + (size_t)(1 + i) * 16384;
        const short* cwl = wplo + (size_t)(1 + i) * 16384;
        gemm_mfma<0><<<gblk, 256, 0, stream>>>(H, cwh, cwl, nullptr, nullptr, HWb);
        agg_kernel<<<N_NODES / 4, 256, 0, stream>>>(HWb, rowptr, srcs, isq,
                                                    conv_b + (size_t)i * CH, T);
        if (i < NL - 1) {
            // H = relu(LN(T)) + H
            ln_kernel<1><<<N_NODES / 4, 256, 0, stream>>>(H, T, ln_g + (size_t)i * CH,
                                                          ln_b + (size_t)i * CH);
            // T = relu(H @ w1 + b1)
            gemm_mfma<1><<<gblk, 256, 0, stream>>>(H, wphi + (size_t)(4 + i) * 16384,
                                                   wplo + (size_t)(4 + i) * 16384,
                                                   ffn_b1 + (size_t)i * CH, nullptr, T);
            // HWb = T @ w2 + b2 + H
            gemm_mfma<2><<<gblk, 256, 0, stream>>>(T, wphi + (size_t)(6 + i) * 16384,
                                                   wplo + (size_t)(6 + i) * 16384,
                                                   ffn_b2 + (size_t)i * CH, H, HWb);
            // H = LN(HWb)
            ln_kernel<0><<<N_NODES / 4, 256, 0, stream>>>(H, HWb, fln_g + (size_t)i * CH,
                                                          fln_b + (size_t)i * CH);
        }
    }

    pool_kernel<<<N_NODES / 64, 256, 0, stream>>>(T, batch, g, cntf);
    cls_kernel<<<NB, CH, 0, stream>>>(g, cntf, cls_w1, cls_b1, cls_w2, cls_b2,
                                      (float*)d_out);
}

// Round 4
// 456.733 us; speedup vs baseline: 2.7189x; 1.3121x over previous
//
#include <hip/hip_runtime.h>
#include <hip/hip_fp16.h>
#include <cstdint>
#include <cstddef>

#define N_NODES 40000
#define N_EDGES 640000
#define CH 128
#define NL 3
#define NB 64
#define LN_EPS 1e-5f

typedef short short8 __attribute__((ext_vector_type(8)));
typedef float floatx4 __attribute__((ext_vector_type(4)));

__device__ __forceinline__ unsigned short bf16_rne(float f) {
    unsigned int u = __float_as_uint(f);
    unsigned int r = u + 0x7FFF + ((u >> 16) & 1);
    return (unsigned short)(r >> 16);
}

// ---------------------------------------------------------------- CSR build

__global__ void deg_kernel(const int* __restrict__ ei, int* __restrict__ degi) {
    int e = blockIdx.x * 256 + threadIdx.x;
    if (e < N_EDGES) atomicAdd(&degi[ei[N_EDGES + e]], 1);
}

__global__ void isq_kernel(const int* __restrict__ degi, float* __restrict__ isq) {
    int n = blockIdx.x * 256 + threadIdx.x;
    if (n < N_NODES) isq[n] = rsqrtf((float)degi[n] + 1.0f);
}

__global__ void scan1_kernel(const int* __restrict__ degi, int* __restrict__ rowptr,
                             int* __restrict__ bsum) {
    __shared__ int s[256];
    int t = threadIdx.x;
    int i = blockIdx.x * 256 + t;
    int v = (i < N_NODES) ? degi[i] : 0;
    s[t] = v;
    __syncthreads();
    for (int off = 1; off < 256; off <<= 1) {
        int add = (t >= off) ? s[t - off] : 0;
        __syncthreads();
        s[t] += add;
        __syncthreads();
    }
    if (i < N_NODES) rowptr[i + 1] = s[t];
    if (t == 255) bsum[blockIdx.x] = s[255];
}

__global__ void scan2_kernel(int* __restrict__ bsum, int* __restrict__ boff, int nb) {
    __shared__ int s[256];
    int t = threadIdx.x;
    int v = (t < nb) ? bsum[t] : 0;
    s[t] = v;
    __syncthreads();
    for (int off = 1; off < 256; off <<= 1) {
        int add = (t >= off) ? s[t - off] : 0;
        __syncthreads();
        s[t] += add;
        __syncthreads();
    }
    if (t < nb) boff[t] = s[t] - v;  // exclusive
}

__global__ void scan3_kernel(int* __restrict__ rowptr, const int* __restrict__ boff) {
    int i = blockIdx.x * 256 + threadIdx.x;
    if (i < N_NODES) rowptr[i + 1] += boff[blockIdx.x];
    if (i == 0 && blockIdx.x == 0) rowptr[0] = 0;
}

__global__ void fill_csr_kernel(const int* __restrict__ ei, const int* __restrict__ rowptr,
                                int* __restrict__ fill, int* __restrict__ srcs) {
    int e = blockIdx.x * 256 + threadIdx.x;
    if (e < N_EDGES) {
        int s = ei[e];
        int d = ei[N_EDGES + e];
        int pos = atomicAdd(&fill[d], 1);
        srcs[rowptr[d] + pos] = s;
    }
}

// ---------------------------------------------------------------- W packing
// Per matrix: [hi 16384 | lo 16384] shorts contiguous (64 KB), B-fragment layout
// for mfma_f32_16x16x32_bf16: frag[((kk*4+quad)*128 + n)*8 + j], k=kk*32+quad*8+j
__global__ void pack_w_kernel(const float* __restrict__ pre_w, const float* __restrict__ conv_w,
                              const float* __restrict__ ffn_w1, const float* __restrict__ ffn_w2,
                              short* __restrict__ wpk, float* __restrict__ zbias) {
    int idx = blockIdx.x * 256 + threadIdx.x;  // 8 * 16384 total
    if (idx < CH) zbias[idx] = 0.f;
    int mat = idx >> 14;
    int e = idx & 16383;
    int k = e >> 7, n = e & 127;
    const float* src;
    switch (mat) {
        case 0: src = pre_w; break;
        case 1: case 2: case 3: src = conv_w + (size_t)(mat - 1) * 16384; break;
        case 4: case 5: src = ffn_w1 + (size_t)(mat - 4) * 16384; break;
        default: src = ffn_w2 + (size_t)(mat - 6) * 16384; break;
    }
    float f = src[e];
    unsigned short h = bf16_rne(f);
    float hf = __uint_as_float((unsigned)h << 16);
    unsigned short l = bf16_rne(f - hf);
    int kk = k >> 5, quad = (k >> 3) & 3, j = k & 7;
    int frag = ((kk * 4 + quad) * 128 + n) * 8 + j;
    wpk[(size_t)mat * 32768 + frag] = (short)h;
    wpk[(size_t)mat * 32768 + 16384 + frag] = (short)l;
}

// ---------------------------------------------------------------- MFMA GEMM
__device__ __forceinline__ void gld_lds16(const short* g, short* l) {
    __builtin_amdgcn_global_load_lds(
        (const __attribute__((address_space(1))) unsigned int*)g,
        (__attribute__((address_space(3))) unsigned int*)l, 16, 0, 0);
}

template <int MODE, int OUTHALF>  // MODE 0: +bias, 1: bias+relu, 2: bias+residual
__launch_bounds__(256, 2)
__global__ void gemm_mfma(const float* __restrict__ A, const short* __restrict__ Wpk,
                          const float* __restrict__ bias, const float* __restrict__ Res,
                          void* __restrict__ OutP) {
    __shared__ short smem[32768];  // hi | lo (64 KB -> 2 blocks/CU)
    const int tid = threadIdx.x;
    const int lane = tid & 63;
    const int wv = tid >> 6;
    const int row0 = blockIdx.x * 64 + wv * 16;
    const int m = lane & 15;
    const int quad = lane >> 4;

#pragma unroll
    for (int r = 0; r < 16; ++r) {
        int off = r * 2048 + tid * 8;  // shorts: 16 rounds x 4 KB
        gld_lds16(Wpk + off, smem + off);
    }

    floatx4 acc[8];
#pragma unroll
    for (int c = 0; c < 8; ++c) acc[c] = (floatx4){0.f, 0.f, 0.f, 0.f};

    const float* arow = A + (size_t)(row0 + m) * CH + quad * 8;
    __syncthreads();

#pragma unroll 1
    for (int kk = 0; kk < 4; ++kk) {
        float4 a0 = *(const float4*)(arow + kk * 32);
        float4 a1 = *(const float4*)(arow + kk * 32 + 4);
        float av[8] = {a0.x, a0.y, a0.z, a0.w, a1.x, a1.y, a1.z, a1.w};
        short8 ahi, alo;
#pragma unroll
        for (int j = 0; j < 8; ++j) {
            unsigned short h = bf16_rne(av[j]);
            ahi[j] = (short)h;
            alo[j] = (short)bf16_rne(av[j] - __uint_as_float((unsigned)h << 16));
        }
        const short* sm_h = smem + ((kk * 4 + quad) * 128 + m) * 8;
        const short* sm_l = sm_h + 16384;
#pragma unroll
        for (int c = 0; c < 8; ++c) {
            short8 bhi = *(const short8*)(sm_h + c * 128);
            short8 blo = *(const short8*)(sm_l + c * 128);
            acc[c] = __builtin_amdgcn_mfma_f32_16x16x32_bf16(ahi, bhi, acc[c], 0, 0, 0);
            acc[c] = __builtin_amdgcn_mfma_f32_16x16x32_bf16(alo, bhi, acc[c], 0, 0, 0);
            acc[c] = __builtin_amdgcn_mfma_f32_16x16x32_bf16(ahi, blo, acc[c], 0, 0, 0);
        }
    }

#pragma unroll
    for (int c = 0; c < 8; ++c) {
        int col = c * 16 + m;
        float bv = bias[col];
#pragma unroll
        for (int r = 0; r < 4; ++r) {
            int row = row0 + quad * 4 + r;
            float v = acc[c][r] + bv;
            if (MODE == 1) v = fmaxf(v, 0.f);
            if (MODE == 2) v += Res[(size_t)row * CH + col];
            if (OUTHALF)
                ((__half*)OutP)[(size_t)row * CH + col] = __float2half(v);
            else
                ((float*)OutP)[(size_t)row * CH + col] = v;
        }
    }
}

// ---------------------------------------------------------------- aggregation
// One wave per dst node, HW in fp16. FUSED=1: Hres = relu(LN(agg+bias)) + Hres.
template <int FUSED>
__launch_bounds__(256)
__global__ void agg_kernel(const __half* __restrict__ HW, const int* __restrict__ rowptr,
                           const int* __restrict__ srcs, const float* __restrict__ isq,
                           const float* __restrict__ bias, const float* __restrict__ gamma,
                           const float* __restrict__ beta, float* __restrict__ Hres,
                           float* __restrict__ Out) {
    const int lane = threadIdx.x & 63;
    const int node = blockIdx.x * 4 + (threadIdx.x >> 6);
    const int start = rowptr[node];
    const int end = rowptr[node + 1];

    float ax = 0.f, ay = 0.f;
    for (int base = start; base < end; base += 64) {
        int idx = base + lane;
        int clamped = (idx < end) ? idx : (end - 1);
        int sl = srcs[clamped];
        float wl = isq[sl];
        int cnt = end - base;
        if (cnt > 64) cnt = 64;
        for (int j = 0; j < cnt; ++j) {
            int s = __shfl(sl, j);
            float w = __shfl(wl, j);
            const __half2 v = *(const __half2*)(HW + (size_t)s * CH + lane * 2);
            float2 vf = __half22float2(v);
            ax = fmaf(w, vf.x, ax);
            ay = fmaf(w, vf.y, ay);
        }
    }
    float d = isq[node];
    const __half2 hv = *(const __half2*)(HW + (size_t)node * CH + lane * 2);
    float2 hf = __half22float2(hv);
    const float2 bb = *(const float2*)(bias + lane * 2);
    float hx = d * ax + d * d * hf.x + bb.x;
    float hy = d * ay + d * d * hf.y + bb.y;

    if (!FUSED) {
        float2 o; o.x = hx; o.y = hy;
        *(float2*)(Out + (size_t)node * CH + lane * 2) = o;
        return;
    }
    float sum = hx + hy;
    float sq = hx * hx + hy * hy;
    for (int msk = 1; msk < 64; msk <<= 1) {
        sum += __shfl_xor(sum, msk);
        sq += __shfl_xor(sq, msk);
    }
    float mean = sum * (1.f / CH);
    float var = sq * (1.f / CH) - mean * mean;
    float rstd = rsqrtf(var + LN_EPS);
    const float2 gg = *(const float2*)(gamma + lane * 2);
    const float2 be = *(const float2*)(beta + lane * 2);
    float y0 = (hx - mean) * rstd * gg.x + be.x;
    float y1 = (hy - mean) * rstd * gg.y + be.y;
    float2* hp = (float2*)(Hres + (size_t)node * CH + lane * 2);
    float2 rr = *hp;
    float2 o;
    o.x = fmaxf(y0, 0.f) + rr.x;
    o.y = fmaxf(y1, 0.f) + rr.y;
    *hp = o;
}

// ---------------------------------------------------------------- layernorm
__launch_bounds__(256)
__global__ void ln_kernel(float* __restrict__ D, const float* __restrict__ S,
                          const float* __restrict__ gamma, const float* __restrict__ beta) {
    const int lane = threadIdx.x & 63;
    const int node = blockIdx.x * 4 + (threadIdx.x >> 6);
    const float2 x = *(const float2*)(S + (size_t)node * CH + lane * 2);
    float sum = x.x + x.y;
    float sq = x.x * x.x + x.y * x.y;
    for (int msk = 1; msk < 64; msk <<= 1) {
        sum += __shfl_xor(sum, msk);
        sq += __shfl_xor(sq, msk);
    }
    float mean = sum * (1.f / CH);
    float var = sq * (1.f / CH) - mean * mean;
    float rstd = rsqrtf(var + LN_EPS);
    const float2 gg = *(const float2*)(gamma + lane * 2);
    const float2 bb = *(const float2*)(beta + lane * 2);
    float2 o;
    o.x = (x.x - mean) * rstd * gg.x + bb.x;
    o.y = (x.y - mean) * rstd * gg.y + bb.y;
    *(float2*)(D + (size_t)node * CH + lane * 2) = o;
}

// ---------------------------------------------------------------- pooling
__launch_bounds__(256)
__global__ void pool_kernel(const float* __restrict__ H, const int* __restrict__ batch,
                            float* __restrict__ g, float* __restrict__ cntf) {
    const int lane = threadIdx.x & 63;
    const int w = blockIdx.x * 4 + (threadIdx.x >> 6);
    const int n0 = w * 16;
    float lx = 0.f, ly = 0.f;
    int run = 0;
    int cur = batch[n0];
    for (int t = 0; t < 16; ++t) {
        int n = n0 + t;
        int b = batch[n];
        if (b != cur) {
            atomicAdd(&g[(size_t)cur * CH + lane * 2], lx);
            atomicAdd(&g[(size_t)cur * CH + lane * 2 + 1], ly);
            if (lane == 0) atomicAdd(&cntf[cur], (float)run);
            lx = ly = 0.f; run = 0; cur = b;
        }
        const float2 v = *(const float2*)(H + (size_t)n * CH + lane * 2);
        lx += v.x; ly += v.y; ++run;
    }
    atomicAdd(&g[(size_t)cur * CH + lane * 2], lx);
    atomicAdd(&g[(size_t)cur * CH + lane * 2 + 1], ly);
    if (lane == 0) atomicAdd(&cntf[cur], (float)run);
}

// ---------------------------------------------------------------- classifier
__launch_bounds__(128)
__global__ void cls_kernel(const float* __restrict__ g, const float* __restrict__ cntf,
                           const float* __restrict__ w1, const float* __restrict__ b1,
                           const float* __restrict__ w2, const float* __restrict__ b2,
                           float* __restrict__ out) {
    __shared__ float gm[CH];
    __shared__ float red[2];
    const int b = blockIdx.x;
    const int t = threadIdx.x;
    float inv = 1.f / fmaxf(cntf[b], 1.f);
    gm[t] = g[(size_t)b * CH + t] * inv;
    __syncthreads();
    float acc = b1[t];
    for (int k = 0; k < CH; ++k) acc = fmaf(gm[k], w1[(size_t)k * CH + t], acc);
    float v = fmaxf(acc, 0.f) * w2[t];
    for (int msk = 1; msk < 64; msk <<= 1) v += __shfl_xor(v, msk);
    if ((t & 63) == 0) red[t >> 6] = v;
    __syncthreads();
    if (t == 0) out[b] = red[0] + red[1] + b2[0];
}

// ---------------------------------------------------------------- launch

extern "C" void kernel_launch(void* const* d_in, const int* in_sizes, int n_in,
                              void* d_out, int out_size, void* d_ws, size_t ws_size,
                              hipStream_t stream) {
    const float* x      = (const float*)d_in[0];
    const int*   ei     = (const int*)d_in[1];
    const int*   batch  = (const int*)d_in[2];
    const float* pre_w  = (const float*)d_in[3];
    const float* pre_b  = (const float*)d_in[4];
    const float* conv_w = (const float*)d_in[5];
    const float* conv_b = (const float*)d_in[6];
    const float* ln_g   = (const float*)d_in[7];
    const float* ln_b   = (const float*)d_in[8];
    const float* ffn_w1 = (const float*)d_in[9];
    const float* ffn_b1 = (const float*)d_in[10];
    const float* ffn_w2 = (const float*)d_in[11];
    const float* ffn_b2 = (const float*)d_in[12];
    const float* fln_g  = (const float*)d_in[13];
    const float* fln_b  = (const float*)d_in[14];
    const float* cls_w1 = (const float*)d_in[15];
    const float* cls_b1 = (const float*)d_in[16];
    const float* cls_w2 = (const float*)d_in[17];
    const float* cls_b2 = (const float*)d_in[18];

    float* H    = (float*)d_ws;                       // 40000*128 f32
    float* T    = H + (size_t)N_NODES * CH;
    float* R    = T + (size_t)N_NODES * CH;           // ffn2 out
    __half* HWh = (__half*)R;                         // alias (disjoint lifetime)
    int*   degi = (int*)(R + (size_t)N_NODES * CH);
    int*   fill = degi + N_NODES;
    float* g    = (float*)(fill + N_NODES);           // zero zone contiguous
    float* cntf = g + (size_t)NB * CH;
    float* isq  = cntf + NB;
    int*  rowptr = (int*)(isq + N_NODES);
    int*  bsum   = rowptr + N_NODES + 1;
    int*  boff   = bsum + 256;
    int*  srcs   = boff + 256;
    short* wpk   = (short*)(srcs + N_EDGES);          // 8 x 32768 shorts
    float* zbias = (float*)(wpk + 8 * 32768);         // CH zeros

    const int nb_scan = (N_NODES + 255) / 256;  // 157

    hipMemsetAsync(degi, 0, (size_t)(2 * N_NODES + NB * CH + NB) * sizeof(int), stream);

    deg_kernel<<<N_EDGES / 256, 256, 0, stream>>>(ei, degi);
    isq_kernel<<<nb_scan, 256, 0, stream>>>(degi, isq);
    scan1_kernel<<<nb_scan, 256, 0, stream>>>(degi, rowptr, bsum);
    scan2_kernel<<<1, 256, 0, stream>>>(bsum, boff, nb_scan);
    scan3_kernel<<<nb_scan, 256, 0, stream>>>(rowptr, boff);
    fill_csr_kernel<<<N_EDGES / 256, 256, 0, stream>>>(ei, rowptr, fill, srcs);
    pack_w_kernel<<<8 * 16384 / 256, 256, 0, stream>>>(pre_w, conv_w, ffn_w1, ffn_w2,
                                                       wpk, zbias);

    const int gblk = N_NODES / 64;   // 625
    const int ablk = N_NODES / 4;    // 10000

    gemm_mfma<0, 0><<<gblk, 256, 0, stream>>>(x, wpk, pre_b, nullptr, H);

    for (int i = 0; i < NL; ++i) {
        // HWh = half(H @ conv_w[i])   (conv bias applied in agg)
        gemm_mfma<0, 1><<<gblk, 256, 0, stream>>>(H, wpk + (size_t)(1 + i) * 32768,
                                                  zbias, nullptr, HWh);
        if (i < NL - 1) {
            agg_kernel<1><<<ablk, 256, 0, stream>>>(HWh, rowptr, srcs, isq,
                                                    conv_b + (size_t)i * CH,
                                                    ln_g + (size_t)i * CH,
                                                    ln_b + (size_t)i * CH, H, nullptr);
            gemm_mfma<1, 0><<<gblk, 256, 0, stream>>>(H, wpk + (size_t)(4 + i) * 32768,
                                                      ffn_b1 + (size_t)i * CH, nullptr, T);
            gemm_mfma<2, 0><<<gblk, 256, 0, stream>>>(T, wpk + (size_t)(6 + i) * 32768,
                                                      ffn_b2 + (size_t)i * CH, H, R);
            ln_kernel<<<ablk, 256, 0, stream>>>(H, R, fln_g + (size_t)i * CH,
                                                fln_b + (size_t)i * CH);
        } else {
            agg_kernel<0><<<ablk, 256, 0, stream>>>(HWh, rowptr, srcs, isq,
                                                    conv_b + (size_t)i * CH,
                                                    nullptr, nullptr, nullptr, T);
        }
    }

    pool_kernel<<<N_NODES / 64, 256, 0, stream>>>(T, batch, g, cntf);
    cls_kernel<<<NB, CH, 0, stream>>>(g, cntf, cls_w1, cls_b1, cls_w2, cls_b2,
                                      (float*)d_out);
}

// Round 7
// 444.223 us; speedup vs baseline: 2.7954x; 1.0282x over previous
//
#include <hip/hip_runtime.h>
#include <hip/hip_fp16.h>
#include <cstdint>
#include <cstddef>

#define N_NODES 40000
#define N_EDGES 640000
#define CH 128
#define NL 3
#define NB 64
#define LN_EPS 1e-5f

typedef short short8 __attribute__((ext_vector_type(8)));
typedef float floatx4 __attribute__((ext_vector_type(4)));

__device__ __forceinline__ unsigned short bf16_rne(float f) {
    unsigned int u = __float_as_uint(f);
    unsigned int r = u + 0x7FFF + ((u >> 16) & 1);
    return (unsigned short)(r >> 16);
}

// ---------------------------------------------------------------- CSR build

__global__ void deg_kernel(const int* __restrict__ ei, int* __restrict__ degi) {
    int e = blockIdx.x * 256 + threadIdx.x;
    if (e < N_EDGES) atomicAdd(&degi[ei[N_EDGES + e]], 1);
}

__global__ void isq_kernel(const int* __restrict__ degi, float* __restrict__ isq) {
    int n = blockIdx.x * 256 + threadIdx.x;
    if (n < N_NODES) isq[n] = rsqrtf((float)degi[n] + 1.0f);
}

__global__ void scan1_kernel(const int* __restrict__ degi, int* __restrict__ rowptr,
                             int* __restrict__ bsum) {
    __shared__ int s[256];
    int t = threadIdx.x;
    int i = blockIdx.x * 256 + t;
    int v = (i < N_NODES) ? degi[i] : 0;
    s[t] = v;
    __syncthreads();
    for (int off = 1; off < 256; off <<= 1) {
        int add = (t >= off) ? s[t - off] : 0;
        __syncthreads();
        s[t] += add;
        __syncthreads();
    }
    if (i < N_NODES) rowptr[i + 1] = s[t];
    if (t == 255) bsum[blockIdx.x] = s[255];
}

__global__ void scan2_kernel(int* __restrict__ bsum, int* __restrict__ boff, int nb) {
    __shared__ int s[256];
    int t = threadIdx.x;
    int v = (t < nb) ? bsum[t] : 0;
    s[t] = v;
    __syncthreads();
    for (int off = 1; off < 256; off <<= 1) {
        int add = (t >= off) ? s[t - off] : 0;
        __syncthreads();
        s[t] += add;
        __syncthreads();
    }
    if (t < nb) boff[t] = s[t] - v;  // exclusive
}

__global__ void scan3_kernel(int* __restrict__ rowptr, const int* __restrict__ boff) {
    int i = blockIdx.x * 256 + threadIdx.x;
    if (i < N_NODES) rowptr[i + 1] += boff[blockIdx.x];
    if (i == 0 && blockIdx.x == 0) rowptr[0] = 0;
}

__global__ void fill_csr_kernel(const int* __restrict__ ei, const int* __restrict__ rowptr,
                                int* __restrict__ fill, int* __restrict__ srcs) {
    int e = blockIdx.x * 256 + threadIdx.x;
    if (e < N_EDGES) {
        int s = ei[e];
        int d = ei[N_EDGES + e];
        int pos = atomicAdd(&fill[d], 1);
        srcs[rowptr[d] + pos] = s;
    }
}

// ---------------------------------------------------------------- W packing
// Per matrix: [hi 16384 | lo 16384] bf16 shorts contiguous (64 KB). B-fragment
// layout for mfma_f32_16x16x32_bf16: frag[((kk*4+quad)*128 + n)*8 + j],
// k = kk*32 + quad*8 + j.  bf16 split keeps lo NORMAL (fp32 exponent range);
// fp16 split FAILED (R5/R6): Wlo ~2e-5 < fp16 min-normal 6e-5 -> flushed.
__global__ void pack_w_kernel(const float* __restrict__ pre_w, const float* __restrict__ conv_w,
                              const float* __restrict__ ffn_w1, const float* __restrict__ ffn_w2,
                              short* __restrict__ wpk, float* __restrict__ zbias) {
    int idx = blockIdx.x * 256 + threadIdx.x;  // 8 * 16384 total
    if (idx < CH) zbias[idx] = 0.f;
    int mat = idx >> 14;
    int e = idx & 16383;
    int k = e >> 7, n = e & 127;
    const float* src;
    switch (mat) {
        case 0: src = pre_w; break;
        case 1: case 2: case 3: src = conv_w + (size_t)(mat - 1) * 16384; break;
        case 4: case 5: src = ffn_w1 + (size_t)(mat - 4) * 16384; break;
        default: src = ffn_w2 + (size_t)(mat - 6) * 16384; break;
    }
    float f = src[e];
    unsigned short h = bf16_rne(f);
    float hf = __uint_as_float((unsigned)h << 16);
    unsigned short l = bf16_rne(f - hf);
    int kk = k >> 5, quad = (k >> 3) & 3, j = k & 7;
    int frag = ((kk * 4 + quad) * 128 + n) * 8 + j;
    wpk[(size_t)mat * 32768 + frag] = (short)h;
    wpk[(size_t)mat * 32768 + 16384 + frag] = (short)l;
}

// ---------------------------------------------------------------- MFMA GEMM
// C = A(fp32) @ W, split-bf16 (3 mfma terms), W hi+lo (64 KB) in LDS.
// Block = 8 waves = 128 rows (W-stage amortized over 2x rows vs R4);
// wave = 16 rows x 128 cols (8 tiles). kk unroll-1 (R2 spill lesson).
__device__ __forceinline__ void gld_lds16(const short* g, short* l) {
    __builtin_amdgcn_global_load_lds(
        (const __attribute__((address_space(1))) unsigned int*)g,
        (__attribute__((address_space(3))) unsigned int*)l, 16, 0, 0);
}

template <int MODE, int OUTHALF>  // MODE 0: +bias, 1: bias+relu, 2: bias+residual
__launch_bounds__(512, 2)
__global__ void gemm_mfma(const float* __restrict__ A, const short* __restrict__ Wpk,
                          const float* __restrict__ bias, const float* __restrict__ Res,
                          void* __restrict__ OutP) {
    __shared__ short smem[32768];  // hi | lo (64 KB -> 2 blocks/CU)
    const int tid = threadIdx.x;
    const int lane = tid & 63;
    const int wv = tid >> 6;
    const int row0 = blockIdx.x * 128 + wv * 16;
    const int m = lane & 15;
    const int quad = lane >> 4;

#pragma unroll
    for (int r = 0; r < 8; ++r) {
        int off = r * 4096 + tid * 8;  // shorts: 8 rounds x 8 KB (512 thr x 16 B)
        gld_lds16(Wpk + off, smem + off);
    }

    floatx4 acc[8];
#pragma unroll
    for (int c = 0; c < 8; ++c) acc[c] = (floatx4){0.f, 0.f, 0.f, 0.f};

    const bool active = (row0 < N_NODES);  // tail block 312: waves 4..7 idle
    const float* arow = A + (size_t)(active ? row0 + m : 0) * CH + quad * 8;
    __syncthreads();

    if (active) {
#pragma unroll 1
        for (int kk = 0; kk < 4; ++kk) {
            float4 a0 = *(const float4*)(arow + kk * 32);
            float4 a1 = *(const float4*)(arow + kk * 32 + 4);
            float av[8] = {a0.x, a0.y, a0.z, a0.w, a1.x, a1.y, a1.z, a1.w};
            short8 ahi, alo;
#pragma unroll
            for (int j = 0; j < 8; ++j) {
                unsigned short h = bf16_rne(av[j]);
                ahi[j] = (short)h;
                alo[j] = (short)bf16_rne(av[j] - __uint_as_float((unsigned)h << 16));
            }
            const short* sm_h = smem + ((kk * 4 + quad) * 128 + m) * 8;
            const short* sm_l = sm_h + 16384;
#pragma unroll
            for (int c = 0; c < 8; ++c) {
                short8 bhi = *(const short8*)(sm_h + c * 128);
                short8 blo = *(const short8*)(sm_l + c * 128);
                acc[c] = __builtin_amdgcn_mfma_f32_16x16x32_bf16(ahi, bhi, acc[c], 0, 0, 0);
                acc[c] = __builtin_amdgcn_mfma_f32_16x16x32_bf16(alo, bhi, acc[c], 0, 0, 0);
                acc[c] = __builtin_amdgcn_mfma_f32_16x16x32_bf16(ahi, blo, acc[c], 0, 0, 0);
            }
        }

#pragma unroll
        for (int c = 0; c < 8; ++c) {
            int col = c * 16 + m;
            float bv = bias[col];
#pragma unroll
            for (int r = 0; r < 4; ++r) {
                int row = row0 + quad * 4 + r;
                float v = acc[c][r] + bv;
                if (MODE == 1) v = fmaxf(v, 0.f);
                if (MODE == 2) v += Res[(size_t)row * CH + col];
                if (OUTHALF)
                    ((__half*)OutP)[(size_t)row * CH + col] = __float2half(v);
                else
                    ((float*)OutP)[(size_t)row * CH + col] = v;
            }
        }
    }
}

// ---------------------------------------------------------------- aggregation
// One wave per dst node, HW in fp16, out fp32. FUSED=1: Hres = relu(LN(agg+bias)) + Hres.
template <int FUSED>
__launch_bounds__(256)
__global__ void agg_kernel(const __half* __restrict__ HW, const int* __restrict__ rowptr,
                           const int* __restrict__ srcs, const float* __restrict__ isq,
                           const float* __restrict__ bias, const float* __restrict__ gamma,
                           const float* __restrict__ beta, float* __restrict__ Hres,
                           float* __restrict__ Out) {
    const int lane = threadIdx.x & 63;
    const int node = blockIdx.x * 4 + (threadIdx.x >> 6);
    const int start = rowptr[node];
    const int end = rowptr[node + 1];

    float ax = 0.f, ay = 0.f;
    for (int base = start; base < end; base += 64) {
        int idx = base + lane;
        int clamped = (idx < end) ? idx : (end - 1);
        int sl = srcs[clamped];
        float wl = isq[sl];
        int cnt = end - base;
        if (cnt > 64) cnt = 64;
        for (int j = 0; j < cnt; ++j) {
            int s = __shfl(sl, j);
            float w = __shfl(wl, j);
            const __half2 v = *(const __half2*)(HW + (size_t)s * CH + lane * 2);
            float2 vf = __half22float2(v);
            ax = fmaf(w, vf.x, ax);
            ay = fmaf(w, vf.y, ay);
        }
    }
    float d = isq[node];
    const __half2 hv = *(const __half2*)(HW + (size_t)node * CH + lane * 2);
    float2 hf = __half22float2(hv);
    const float2 bb = *(const float2*)(bias + lane * 2);
    float hx = d * ax + d * d * hf.x + bb.x;
    float hy = d * ay + d * d * hf.y + bb.y;

    if (!FUSED) {
        float2 o; o.x = hx; o.y = hy;
        *(float2*)(Out + (size_t)node * CH + lane * 2) = o;
        return;
    }
    float sum = hx + hy;
    float sq = hx * hx + hy * hy;
    for (int msk = 1; msk < 64; msk <<= 1) {
        sum += __shfl_xor(sum, msk);
        sq += __shfl_xor(sq, msk);
    }
    float mean = sum * (1.f / CH);
    float var = sq * (1.f / CH) - mean * mean;
    float rstd = rsqrtf(var + LN_EPS);
    const float2 gg = *(const float2*)(gamma + lane * 2);
    const float2 be = *(const float2*)(beta + lane * 2);
    float y0 = (hx - mean) * rstd * gg.x + be.x;
    float y1 = (hy - mean) * rstd * gg.y + be.y;
    float2* hp = (float2*)(Hres + (size_t)node * CH + lane * 2);
    float2 rr = *hp;
    float2 o;
    o.x = fmaxf(y0, 0.f) + rr.x;
    o.y = fmaxf(y1, 0.f) + rr.y;
    *hp = o;
}

// ---------------------------------------------------------------- layernorm
__launch_bounds__(256)
__global__ void ln_kernel(float* __restrict__ D, const float* __restrict__ S,
                          const float* __restrict__ gamma, const float* __restrict__ beta) {
    const int lane = threadIdx.x & 63;
    const int node = blockIdx.x * 4 + (threadIdx.x >> 6);
    const float2 x = *(const float2*)(S + (size_t)node * CH + lane * 2);
    float sum = x.x + x.y;
    float sq = x.x * x.x + x.y * x.y;
    for (int msk = 1; msk < 64; msk <<= 1) {
        sum += __shfl_xor(sum, msk);
        sq += __shfl_xor(sq, msk);
    }
    float mean = sum * (1.f / CH);
    float var = sq * (1.f / CH) - mean * mean;
    float rstd = rsqrtf(var + LN_EPS);
    const float2 gg = *(const float2*)(gamma + lane * 2);
    const float2 bb = *(const float2*)(beta + lane * 2);
    float2 o;
    o.x = (x.x - mean) * rstd * gg.x + bb.x;
    o.y = (x.y - mean) * rstd * gg.y + bb.y;
    *(float2*)(D + (size_t)node * CH + lane * 2) = o;
}

// ---------------------------------------------------------------- pooling
__launch_bounds__(256)
__global__ void pool_kernel(const float* __restrict__ H, const int* __restrict__ batch,
                            float* __restrict__ g, float* __restrict__ cntf) {
    const int lane = threadIdx.x & 63;
    const int w = blockIdx.x * 4 + (threadIdx.x >> 6);
    const int n0 = w * 16;
    float lx = 0.f, ly = 0.f;
    int run = 0;
    int cur = batch[n0];
    for (int t = 0; t < 16; ++t) {
        int n = n0 + t;
        int b = batch[n];
        if (b != cur) {
            atomicAdd(&g[(size_t)cur * CH + lane * 2], lx);
            atomicAdd(&g[(size_t)cur * CH + lane * 2 + 1], ly);
            if (lane == 0) atomicAdd(&cntf[cur], (float)run);
            lx = ly = 0.f; run = 0; cur = b;
        }
        const float2 v = *(const float2*)(H + (size_t)n * CH + lane * 2);
        lx += v.x; ly += v.y; ++run;
    }
    atomicAdd(&g[(size_t)cur * CH + lane * 2], lx);
    atomicAdd(&g[(size_t)cur * CH + lane * 2 + 1], ly);
    if (lane == 0) atomicAdd(&cntf[cur], (float)run);
}

// ---------------------------------------------------------------- classifier
__launch_bounds__(128)
__global__ void cls_kernel(const float* __restrict__ g, const float* __restrict__ cntf,
                           const float* __restrict__ w1, const float* __restrict__ b1,
                           const float* __restrict__ w2, const float* __restrict__ b2,
                           float* __restrict__ out) {
    __shared__ float gm[CH];
    __shared__ float red[2];
    const int b = blockIdx.x;
    const int t = threadIdx.x;
    float inv = 1.f / fmaxf(cntf[b], 1.f);
    gm[t] = g[(size_t)b * CH + t] * inv;
    __syncthreads();
    float acc = b1[t];
    for (int k = 0; k < CH; ++k) acc = fmaf(gm[k], w1[(size_t)k * CH + t], acc);
    float v = fmaxf(acc, 0.f) * w2[t];
    for (int msk = 1; msk < 64; msk <<= 1) v += __shfl_xor(v, msk);
    if ((t & 63) == 0) red[t >> 6] = v;
    __syncthreads();
    if (t == 0) out[b] = red[0] + red[1] + b2[0];
}

// ---------------------------------------------------------------- launch

extern "C" void kernel_launch(void* const* d_in, const int* in_sizes, int n_in,
                              void* d_out, int out_size, void* d_ws, size_t ws_size,
                              hipStream_t stream) {
    const float* x      = (const float*)d_in[0];
    const int*   ei     = (const int*)d_in[1];
    const int*   batch  = (const int*)d_in[2];
    const float* pre_w  = (const float*)d_in[3];
    const float* pre_b  = (const float*)d_in[4];
    const float* conv_w = (const float*)d_in[5];
    const float* conv_b = (const float*)d_in[6];
    const float* ln_g   = (const float*)d_in[7];
    const float* ln_b   = (const float*)d_in[8];
    const float* ffn_w1 = (const float*)d_in[9];
    const float* ffn_b1 = (const float*)d_in[10];
    const float* ffn_w2 = (const float*)d_in[11];
    const float* ffn_b2 = (const float*)d_in[12];
    const float* fln_g  = (const float*)d_in[13];
    const float* fln_b  = (const float*)d_in[14];
    const float* cls_w1 = (const float*)d_in[15];
    const float* cls_b1 = (const float*)d_in[16];
    const float* cls_w2 = (const float*)d_in[17];
    const float* cls_b2 = (const float*)d_in[18];

    float* H    = (float*)d_ws;                       // 40000*128 f32 (residual)
    float* T    = H + (size_t)N_NODES * CH;           // f32
    float* R    = T + (size_t)N_NODES * CH;           // f32 (ffn2 out)
    __half* HWh = (__half*)R;                         // alias (disjoint lifetime)
    int*   degi = (int*)(R + (size_t)N_NODES * CH);
    int*   fill = degi + N_NODES;
    float* g    = (float*)(fill + N_NODES);           // zero zone contiguous
    float* cntf = g + (size_t)NB * CH;
    float* isq  = cntf + NB;
    int*  rowptr = (int*)(isq + N_NODES);
    int*  bsum   = rowptr + N_NODES + 1;
    int*  boff   = bsum + 256;
    int*  srcs   = boff + 256;
    short* wpk   = (short*)(srcs + N_EDGES);          // 8 x 32768 shorts
    float* zbias = (float*)(wpk + 8 * 32768);         // CH zeros

    const int nb_scan = (N_NODES + 255) / 256;  // 157

    hipMemsetAsync(degi, 0, (size_t)(2 * N_NODES + NB * CH + NB) * sizeof(int), stream);

    deg_kernel<<<N_EDGES / 256, 256, 0, stream>>>(ei, degi);
    isq_kernel<<<nb_scan, 256, 0, stream>>>(degi, isq);
    scan1_kernel<<<nb_scan, 256, 0, stream>>>(degi, rowptr, bsum);
    scan2_kernel<<<1, 256, 0, stream>>>(bsum, boff, nb_scan);
    scan3_kernel<<<nb_scan, 256, 0, stream>>>(rowptr, boff);
    fill_csr_kernel<<<N_EDGES / 256, 256, 0, stream>>>(ei, rowptr, fill, srcs);
    pack_w_kernel<<<8 * 16384 / 256, 256, 0, stream>>>(pre_w, conv_w, ffn_w1, ffn_w2,
                                                       wpk, zbias);

    const int gblk = (N_NODES + 127) / 128;  // 313 (tail-guarded)
    const int lblk = N_NODES / 4;            // 10000

    // pre-scaler: H = x @ pre_w + pre_b   (fp32 out)
    gemm_mfma<0, 0><<<gblk, 512, 0, stream>>>(x, wpk, pre_b, nullptr, H);

    for (int i = 0; i < NL; ++i) {
        // HWh = fp16(H @ conv_w[i])   (conv bias applied in agg)
        gemm_mfma<0, 1><<<gblk, 512, 0, stream>>>(H, wpk + (size_t)(1 + i) * 32768,
                                                  zbias, nullptr, HWh);
        if (i < NL - 1) {
            // H = relu(LN(agg(HWh)+conv_b)) + H   (fused)
            agg_kernel<1><<<lblk, 256, 0, stream>>>(HWh, rowptr, srcs, isq,
                                                    conv_b + (size_t)i * CH,
                                                    ln_g + (size_t)i * CH,
                                                    ln_b + (size_t)i * CH, H, nullptr);
            // T = relu(H @ w1 + b1)
            gemm_mfma<1, 0><<<gblk, 512, 0, stream>>>(H, wpk + (size_t)(4 + i) * 32768,
                                                      ffn_b1 + (size_t)i * CH, nullptr, T);
            // R = T @ w2 + b2 + H
            gemm_mfma<2, 0><<<gblk, 512, 0, stream>>>(T, wpk + (size_t)(6 + i) * 32768,
                                                      ffn_b2 + (size_t)i * CH, H, R);
            // H = LN(R)
            ln_kernel<<<lblk, 256, 0, stream>>>(H, R, fln_g + (size_t)i * CH,
                                                fln_b + (size_t)i * CH);
        } else {
            // T = agg(HWh) + conv_b   (fp32)
            agg_kernel<0><<<lblk, 256, 0, stream>>>(HWh, rowptr, srcs, isq,
                                                    conv_b + (size_t)i * CH,
                                                    nullptr, nullptr, nullptr, T);
        }
    }

    pool_kernel<<<N_NODES / 64, 256, 0, stream>>>(T, batch, g, cntf);
    cls_kernel<<<NB, CH, 0, stream>>>(g, cntf, cls_w1, cls_b1, cls_w2, cls_b2,
                                      (float*)d_out);
}